// Round 4
// baseline (1351.521 us; speedup 1.0000x reference)
//
#include <hip/hip_runtime.h>

#define FSZ 5
#define CHUNK 16

// Problem constants (from reference setup_inputs)
#define B_ 2
#define C_ 64
#define H_ 256
#define W_ 256
#define HIN (H_ + FSZ - 1)   // 260
#define WIN (W_ + FSZ - 1)   // 260
#define PLANE (HIN * WIN)    // 67600 pixels per (b,c) plane

// ---------------------------------------------------------------------------
// Kernel A: transpose [b][c][y][x] -> ws[b][(y,x)][c]  (channels-last).
// LDS-tiled 64x64 so both global read and global write are coalesced.
// ---------------------------------------------------------------------------
__global__ __launch_bounds__(256) void transpose_cl_kernel(
    const float* __restrict__ inp, float* __restrict__ ws)
{
    __shared__ float t[64][65];            // +1 pad: conflict-free both phases
    const int NP64 = (PLANE + 63) / 64;    // 1057 pixel tiles
    int bid = blockIdx.x;
    const int b  = bid / NP64;
    const int p0 = (bid % NP64) * 64;
    const float* ib = inp + (size_t)b * C_ * PLANE;
    float*       wb = ws  + (size_t)b * PLANE * C_;
    const int tid = threadIdx.x;

    #pragma unroll
    for (int it = 0; it < 16; ++it) {
        const int e = it * 256 + tid;
        const int c = e >> 6;              // 0..63
        const int p = e & 63;              // 0..63
        const int pp = p0 + p;
        t[p][c] = (pp < PLANE) ? ib[(size_t)c * PLANE + pp] : 0.f;
    }
    __syncthreads();
    #pragma unroll
    for (int it = 0; it < 16; ++it) {
        const int e = it * 256 + tid;
        const int p = e >> 6;
        const int c = e & 63;
        const int pp = p0 + p;
        if (pp < PLANE) wb[(size_t)pp * C_ + c] = t[p][c];
    }
}

// ---------------------------------------------------------------------------
// Kernel B: gather from channels-last ws. One thread = one output pixel x 16
// channels; each bilinear corner is ONE fully-used 64B line (4x float4).
// ---------------------------------------------------------------------------
#define FMA4(A, Wt, V) \
    A.x = fmaf(Wt, V.x, A.x); A.y = fmaf(Wt, V.y, A.y); \
    A.z = fmaf(Wt, V.z, A.z); A.w = fmaf(Wt, V.w, A.w);

__global__ __launch_bounds__(256) void dsepconv_cl_kernel(
    const float* __restrict__ ws,
    const float* __restrict__ vertical,
    const float* __restrict__ horizontal,
    const float* __restrict__ offx,
    const float* __restrict__ offy,
    const float* __restrict__ mask,
    float* __restrict__ out)
{
    const int NCH = C_ / CHUNK;            // 4 channel chunks
    const int x = threadIdx.x;             // 0..255 == W
    int bid = blockIdx.x;
    const int cc = bid % NCH; bid /= NCH;
    const int y  = bid % H_;  bid /= H_;
    const int b  = bid;
    const int c0 = cc * CHUNK;

    const int HW = H_ * W_;
    const int pix = y * W_ + x;

    const float* vert = vertical   + (size_t)(b * FSZ) * HW + pix;
    const float* horz = horizontal + (size_t)(b * FSZ) * HW + pix;
    const float* ox   = offx + (size_t)(b * FSZ * FSZ) * HW + pix;
    const float* oy   = offy + (size_t)(b * FSZ * FSZ) * HW + pix;
    const float* mk   = mask + (size_t)(b * FSZ * FSZ) * HW + pix;
    const float* wsb  = ws + (size_t)b * PLANE * C_ + c0;  // chunk base

    float4 a0 = {0,0,0,0}, a1 = {0,0,0,0}, a2 = {0,0,0,0}, a3 = {0,0,0,0};

    float hj_r[FSZ];
    #pragma unroll
    for (int j = 0; j < FSZ; ++j) hj_r[j] = horz[j * HW];

    for (int i = 0; i < FSZ; ++i) {
        const float vi = vert[i * HW];
        #pragma unroll
        for (int j = 0; j < FSZ; ++j) {
            const int k = i * FSZ + j;
            const float offy_v = oy[k * HW];
            const float offx_v = ox[k * HW];
            const float m_v    = mk[k * HW];

            const float pyf = (float)(y + i) + offy_v;
            const float pxf = (float)(x + j) + offx_v;
            const float y0f = floorf(pyf);
            const float x0f = floorf(pxf);
            const float ay = pyf - y0f;
            const float ax = pxf - x0f;

            int y0 = (int)y0f;
            int x0 = (int)x0f;
            int y1 = y0 + 1;
            int x1 = x0 + 1;
            y0 = min(max(y0, 0), HIN - 1);
            y1 = min(max(y1, 0), HIN - 1);
            x0 = min(max(x0, 0), WIN - 1);
            x1 = min(max(x1, 0), WIN - 1);

            const float w   = vi * hj_r[j] * m_v;
            const float w00 = w * (1.f - ay) * (1.f - ax);
            const float w01 = w * (1.f - ay) * ax;
            const float w10 = w * ay * (1.f - ax);
            const float w11 = w * ay * ax;

            const float4* p00 = (const float4*)(wsb + (size_t)(y0 * WIN + x0) * C_);
            const float4* p01 = (const float4*)(wsb + (size_t)(y0 * WIN + x1) * C_);
            const float4* p10 = (const float4*)(wsb + (size_t)(y1 * WIN + x0) * C_);
            const float4* p11 = (const float4*)(wsb + (size_t)(y1 * WIN + x1) * C_);

            const float4 v00a = p00[0], v00b = p00[1], v00c = p00[2], v00d = p00[3];
            const float4 v01a = p01[0], v01b = p01[1], v01c = p01[2], v01d = p01[3];
            const float4 v10a = p10[0], v10b = p10[1], v10c = p10[2], v10d = p10[3];
            const float4 v11a = p11[0], v11b = p11[1], v11c = p11[2], v11d = p11[3];

            FMA4(a0, w00, v00a); FMA4(a1, w00, v00b); FMA4(a2, w00, v00c); FMA4(a3, w00, v00d);
            FMA4(a0, w01, v01a); FMA4(a1, w01, v01b); FMA4(a2, w01, v01c); FMA4(a3, w01, v01d);
            FMA4(a0, w10, v10a); FMA4(a1, w10, v10b); FMA4(a2, w10, v10c); FMA4(a3, w10, v10d);
            FMA4(a0, w11, v11a); FMA4(a1, w11, v11b); FMA4(a2, w11, v11c); FMA4(a3, w11, v11d);
        }
    }

    float* outp = out + (size_t)(b * C_ + c0) * HW + pix;
    outp[0 * HW] = a0.x;  outp[1 * HW] = a0.y;  outp[2 * HW] = a0.z;  outp[3 * HW] = a0.w;
    outp[4 * HW] = a1.x;  outp[5 * HW] = a1.y;  outp[6 * HW] = a1.z;  outp[7 * HW] = a1.w;
    outp[8 * HW] = a2.x;  outp[9 * HW] = a2.y;  outp[10 * HW] = a2.z; outp[11 * HW] = a2.w;
    outp[12 * HW] = a3.x; outp[13 * HW] = a3.y; outp[14 * HW] = a3.z; outp[15 * HW] = a3.w;
}

// ---------------------------------------------------------------------------
// Fallback (R1, proven-correct, ~613us): channels-first scattered gather.
// Used only if ws_size can't hold the transposed input.
// ---------------------------------------------------------------------------
__global__ __launch_bounds__(256) void dsepconv_kernel(
    const float* __restrict__ inp,
    const float* __restrict__ vertical,
    const float* __restrict__ horizontal,
    const float* __restrict__ offx,
    const float* __restrict__ offy,
    const float* __restrict__ mask,
    float* __restrict__ out)
{
    const int NCH = C_ / CHUNK;
    const int x = threadIdx.x;
    int bid = blockIdx.x;
    const int cc = bid % NCH; bid /= NCH;
    const int y  = bid % H_;  bid /= H_;
    const int b  = bid;
    const int c0 = cc * CHUNK;

    const int HW = H_ * W_;
    const int pix = y * W_ + x;

    const float* vert = vertical   + (size_t)(b * FSZ) * HW + pix;
    const float* horz = horizontal + (size_t)(b * FSZ) * HW + pix;
    const float* ox   = offx + (size_t)(b * FSZ * FSZ) * HW + pix;
    const float* oy   = offy + (size_t)(b * FSZ * FSZ) * HW + pix;
    const float* mk   = mask + (size_t)(b * FSZ * FSZ) * HW + pix;
    const float* inb  = inp + (size_t)(b * C_ + c0) * PLANE;

    float acc[CHUNK];
    #pragma unroll
    for (int c = 0; c < CHUNK; ++c) acc[c] = 0.f;

    float hj_r[FSZ];
    #pragma unroll
    for (int j = 0; j < FSZ; ++j) hj_r[j] = horz[j * HW];

    for (int i = 0; i < FSZ; ++i) {
        const float vi = vert[i * HW];
        #pragma unroll
        for (int j = 0; j < FSZ; ++j) {
            const int k = i * FSZ + j;
            const float offy_v = oy[k * HW];
            const float offx_v = ox[k * HW];
            const float m_v    = mk[k * HW];

            const float pyf = (float)(y + i) + offy_v;
            const float pxf = (float)(x + j) + offx_v;
            const float y0f = floorf(pyf);
            const float x0f = floorf(pxf);
            const float ay = pyf - y0f;
            const float ax = pxf - x0f;

            int y0 = (int)y0f;
            int x0 = (int)x0f;
            int y1 = y0 + 1;
            int x1 = x0 + 1;
            y0 = min(max(y0, 0), HIN - 1);
            y1 = min(max(y1, 0), HIN - 1);
            x0 = min(max(x0, 0), WIN - 1);
            x1 = min(max(x1, 0), WIN - 1);

            const float w   = vi * hj_r[j] * m_v;
            const float w00 = w * (1.f - ay) * (1.f - ax);
            const float w01 = w * (1.f - ay) * ax;
            const float w10 = w * ay * (1.f - ax);
            const float w11 = w * ay * ax;

            const int i00 = y0 * WIN + x0;
            const int i01 = y0 * WIN + x1;
            const int i10 = y1 * WIN + x0;
            const int i11 = y1 * WIN + x1;

            #pragma unroll
            for (int c = 0; c < CHUNK; ++c) {
                const float* p = inb + (size_t)c * PLANE;
                float a = acc[c];
                a = fmaf(w00, p[i00], a);
                a = fmaf(w01, p[i01], a);
                a = fmaf(w10, p[i10], a);
                a = fmaf(w11, p[i11], a);
                acc[c] = a;
            }
        }
    }

    float* outp = out + (size_t)(b * C_ + c0) * HW + pix;
    #pragma unroll
    for (int c = 0; c < CHUNK; ++c)
        outp[(size_t)c * HW] = acc[c];
}

extern "C" void kernel_launch(void* const* d_in, const int* in_sizes, int n_in,
                              void* d_out, int out_size, void* d_ws, size_t ws_size,
                              hipStream_t stream) {
    const float* inp        = (const float*)d_in[0];
    const float* vertical   = (const float*)d_in[1];
    const float* horizontal = (const float*)d_in[2];
    const float* offset_x   = (const float*)d_in[3];
    const float* offset_y   = (const float*)d_in[4];
    const float* mask       = (const float*)d_in[5];
    float* out              = (float*)d_out;

    const int NCH = C_ / CHUNK;
    const size_t need = (size_t)B_ * PLANE * C_ * sizeof(float);  // 34.6 MB

    if (ws_size >= need) {
        float* ws = (float*)d_ws;
        const int NP64 = (PLANE + 63) / 64;
        transpose_cl_kernel<<<dim3(B_ * NP64), dim3(256), 0, stream>>>(inp, ws);
        dsepconv_cl_kernel<<<dim3(B_ * H_ * NCH), dim3(W_), 0, stream>>>(
            ws, vertical, horizontal, offset_x, offset_y, mask, out);
    } else {
        dsepconv_kernel<<<dim3(B_ * H_ * NCH), dim3(W_), 0, stream>>>(
            inp, vertical, horizontal, offset_x, offset_y, mask, out);
    }
}

// Round 5
// 160.657 us; speedup vs baseline: 8.4125x; 8.4125x over previous
//
#include <hip/hip_runtime.h>

#define FSZ 5

// Problem constants (from reference setup_inputs)
#define B_ 2
#define C_ 64
#define H_ 256
#define W_ 256
#define HIN (H_ + FSZ - 1)   // 260
#define WIN (W_ + FSZ - 1)   // 260
#define PLANE (HIN * WIN)    // 67600 pixels per (b,c) plane

#define PXB 16               // pixels per block (gather kernel)
#define NXG (W_ / PXB)       // 16 x-groups per row

// ---------------------------------------------------------------------------
// Kernel A: transpose [b][c][y][x] -> ws[b][(y,x)][c]  (channels-last).
// Proven in R3 (~26us).
// ---------------------------------------------------------------------------
__global__ __launch_bounds__(256) void transpose_cl_kernel(
    const float* __restrict__ inp, float* __restrict__ ws)
{
    __shared__ float t[64][65];            // +1 pad: conflict-free both phases
    const int NP64 = (PLANE + 63) / 64;    // 1057 pixel tiles
    int bid = blockIdx.x;
    const int b  = bid / NP64;
    const int p0 = (bid % NP64) * 64;
    const float* ib = inp + (size_t)b * C_ * PLANE;
    float*       wb = ws  + (size_t)b * PLANE * C_;
    const int tid = threadIdx.x;

    #pragma unroll
    for (int it = 0; it < 16; ++it) {
        const int e = it * 256 + tid;
        const int c = e >> 6;              // 0..63
        const int p = e & 63;              // 0..63
        const int pp = p0 + p;
        t[p][c] = (pp < PLANE) ? ib[(size_t)c * PLANE + pp] : 0.f;
    }
    __syncthreads();
    #pragma unroll
    for (int it = 0; it < 16; ++it) {
        const int e = it * 256 + tid;
        const int p = e >> 6;
        const int c = e & 63;
        const int pp = p0 + p;
        if (pp < PLANE) wb[(size_t)pp * C_ + c] = t[p][c];
    }
}

// ---------------------------------------------------------------------------
// Kernel B (new): channels-last gather, thread = (pixel, 4-channel group).
// lane = pl*16 + cg  -> per corner, 16 consecutive lanes read one pixel's
// 256B contiguously (16 fully-used 64B lines per wave-instr).
// Block = 16 pixels -> ~86KB offset-window footprint; y-adjacent same-x
// blocks are 16 bids apart (== same XCD under %8 round-robin) so the L2
// window per XCD stays < 4MB.
// ---------------------------------------------------------------------------
__global__ __launch_bounds__(256) void dsepconv_cl2_kernel(
    const float* __restrict__ ws,
    const float* __restrict__ vertical,
    const float* __restrict__ horizontal,
    const float* __restrict__ offx,
    const float* __restrict__ offy,
    const float* __restrict__ mask,
    float* __restrict__ out)
{
    const int t  = threadIdx.x;
    const int cg = t & 15;                 // 4-channel group: c = cg*4..cg*4+3
    const int pl = t >> 4;                 // pixel within block, 0..15
    int bid = blockIdx.x;
    const int xg = bid % NXG; bid /= NXG;
    const int y  = bid % H_;  bid /= H_;
    const int b  = bid;
    const int x  = xg * PXB + pl;

    const int HW = H_ * W_;
    const int pix = y * W_ + x;

    const float* vert = vertical   + (size_t)(b * FSZ) * HW + pix;
    const float* horz = horizontal + (size_t)(b * FSZ) * HW + pix;
    const float* ox   = offx + (size_t)(b * FSZ * FSZ) * HW + pix;
    const float* oy   = offy + (size_t)(b * FSZ * FSZ) * HW + pix;
    const float* mk   = mask + (size_t)(b * FSZ * FSZ) * HW + pix;
    const float* wsb  = ws + (size_t)b * PLANE * C_ + (size_t)cg * 4;

    float4 acc = {0.f, 0.f, 0.f, 0.f};

    float hj_r[FSZ];
    #pragma unroll
    for (int j = 0; j < FSZ; ++j) hj_r[j] = horz[j * HW];

    for (int i = 0; i < FSZ; ++i) {
        const float vi = vert[i * HW];
        #pragma unroll
        for (int j = 0; j < FSZ; ++j) {
            const int k = i * FSZ + j;
            const float offy_v = oy[k * HW];
            const float offx_v = ox[k * HW];
            const float m_v    = mk[k * HW];

            const float pyf = (float)(y + i) + offy_v;
            const float pxf = (float)(x + j) + offx_v;
            const float y0f = floorf(pyf);
            const float x0f = floorf(pxf);
            const float ay = pyf - y0f;
            const float ax = pxf - x0f;

            int y0 = (int)y0f;
            int x0 = (int)x0f;
            int y1 = y0 + 1;
            int x1 = x0 + 1;
            y0 = min(max(y0, 0), HIN - 1);
            y1 = min(max(y1, 0), HIN - 1);
            x0 = min(max(x0, 0), WIN - 1);
            x1 = min(max(x1, 0), WIN - 1);

            const float w   = vi * hj_r[j] * m_v;
            const float w00 = w * (1.f - ay) * (1.f - ax);
            const float w01 = w * (1.f - ay) * ax;
            const float w10 = w * ay * (1.f - ax);
            const float w11 = w * ay * ax;

            const float4 v00 = *(const float4*)(wsb + (size_t)(y0 * WIN + x0) * C_);
            const float4 v01 = *(const float4*)(wsb + (size_t)(y0 * WIN + x1) * C_);
            const float4 v10 = *(const float4*)(wsb + (size_t)(y1 * WIN + x0) * C_);
            const float4 v11 = *(const float4*)(wsb + (size_t)(y1 * WIN + x1) * C_);

            acc.x = fmaf(w00, v00.x, acc.x);
            acc.y = fmaf(w00, v00.y, acc.y);
            acc.z = fmaf(w00, v00.z, acc.z);
            acc.w = fmaf(w00, v00.w, acc.w);
            acc.x = fmaf(w01, v01.x, acc.x);
            acc.y = fmaf(w01, v01.y, acc.y);
            acc.z = fmaf(w01, v01.z, acc.z);
            acc.w = fmaf(w01, v01.w, acc.w);
            acc.x = fmaf(w10, v10.x, acc.x);
            acc.y = fmaf(w10, v10.y, acc.y);
            acc.z = fmaf(w10, v10.z, acc.z);
            acc.w = fmaf(w10, v10.w, acc.w);
            acc.x = fmaf(w11, v11.x, acc.x);
            acc.y = fmaf(w11, v11.y, acc.y);
            acc.z = fmaf(w11, v11.z, acc.z);
            acc.w = fmaf(w11, v11.w, acc.w);
        }
    }

    // output is channels-first [b][c][y][x]
    float* outp = out + ((size_t)(b * C_ + cg * 4)) * HW + pix;
    outp[0 * HW] = acc.x;
    outp[1 * HW] = acc.y;
    outp[2 * HW] = acc.z;
    outp[3 * HW] = acc.w;
}

// ---------------------------------------------------------------------------
// Fallback (R1, proven-correct, ~613us): channels-first scattered gather.
// ---------------------------------------------------------------------------
#define CHUNK 16
__global__ __launch_bounds__(256) void dsepconv_kernel(
    const float* __restrict__ inp,
    const float* __restrict__ vertical,
    const float* __restrict__ horizontal,
    const float* __restrict__ offx,
    const float* __restrict__ offy,
    const float* __restrict__ mask,
    float* __restrict__ out)
{
    const int NCH = C_ / CHUNK;
    const int x = threadIdx.x;
    int bid = blockIdx.x;
    const int cc = bid % NCH; bid /= NCH;
    const int y  = bid % H_;  bid /= H_;
    const int b  = bid;
    const int c0 = cc * CHUNK;

    const int HW = H_ * W_;
    const int pix = y * W_ + x;

    const float* vert = vertical   + (size_t)(b * FSZ) * HW + pix;
    const float* horz = horizontal + (size_t)(b * FSZ) * HW + pix;
    const float* ox   = offx + (size_t)(b * FSZ * FSZ) * HW + pix;
    const float* oy   = offy + (size_t)(b * FSZ * FSZ) * HW + pix;
    const float* mk   = mask + (size_t)(b * FSZ * FSZ) * HW + pix;
    const float* inb  = inp + (size_t)(b * C_ + c0) * PLANE;

    float acc[CHUNK];
    #pragma unroll
    for (int c = 0; c < CHUNK; ++c) acc[c] = 0.f;

    float hj_r[FSZ];
    #pragma unroll
    for (int j = 0; j < FSZ; ++j) hj_r[j] = horz[j * HW];

    for (int i = 0; i < FSZ; ++i) {
        const float vi = vert[i * HW];
        #pragma unroll
        for (int j = 0; j < FSZ; ++j) {
            const int k = i * FSZ + j;
            const float offy_v = oy[k * HW];
            const float offx_v = ox[k * HW];
            const float m_v    = mk[k * HW];

            const float pyf = (float)(y + i) + offy_v;
            const float pxf = (float)(x + j) + offx_v;
            const float y0f = floorf(pyf);
            const float x0f = floorf(pxf);
            const float ay = pyf - y0f;
            const float ax = pxf - x0f;

            int y0 = (int)y0f;
            int x0 = (int)x0f;
            int y1 = y0 + 1;
            int x1 = x0 + 1;
            y0 = min(max(y0, 0), HIN - 1);
            y1 = min(max(y1, 0), HIN - 1);
            x0 = min(max(x0, 0), WIN - 1);
            x1 = min(max(x1, 0), WIN - 1);

            const float w   = vi * hj_r[j] * m_v;
            const float w00 = w * (1.f - ay) * (1.f - ax);
            const float w01 = w * (1.f - ay) * ax;
            const float w10 = w * ay * (1.f - ax);
            const float w11 = w * ay * ax;

            const int i00 = y0 * WIN + x0;
            const int i01 = y0 * WIN + x1;
            const int i10 = y1 * WIN + x0;
            const int i11 = y1 * WIN + x1;

            #pragma unroll
            for (int c = 0; c < CHUNK; ++c) {
                const float* p = inb + (size_t)c * PLANE;
                float a = acc[c];
                a = fmaf(w00, p[i00], a);
                a = fmaf(w01, p[i01], a);
                a = fmaf(w10, p[i10], a);
                a = fmaf(w11, p[i11], a);
                acc[c] = a;
            }
        }
    }

    float* outp = out + (size_t)(b * C_ + c0) * HW + pix;
    #pragma unroll
    for (int c = 0; c < CHUNK; ++c)
        outp[(size_t)c * HW] = acc[c];
}

extern "C" void kernel_launch(void* const* d_in, const int* in_sizes, int n_in,
                              void* d_out, int out_size, void* d_ws, size_t ws_size,
                              hipStream_t stream) {
    const float* inp        = (const float*)d_in[0];
    const float* vertical   = (const float*)d_in[1];
    const float* horizontal = (const float*)d_in[2];
    const float* offset_x   = (const float*)d_in[3];
    const float* offset_y   = (const float*)d_in[4];
    const float* mask       = (const float*)d_in[5];
    float* out              = (float*)d_out;

    const size_t need = (size_t)B_ * PLANE * C_ * sizeof(float);  // 34.6 MB

    if (ws_size >= need) {
        float* ws = (float*)d_ws;
        const int NP64 = (PLANE + 63) / 64;
        transpose_cl_kernel<<<dim3(B_ * NP64), dim3(256), 0, stream>>>(inp, ws);
        dsepconv_cl2_kernel<<<dim3(B_ * H_ * NXG), dim3(256), 0, stream>>>(
            ws, vertical, horizontal, offset_x, offset_y, mask, out);
    } else {
        const int NCH = C_ / CHUNK;
        dsepconv_kernel<<<dim3(B_ * H_ * NCH), dim3(W_), 0, stream>>>(
            inp, vertical, horizontal, offset_x, offset_y, mask, out);
    }
}

// Round 6
// 99.509 us; speedup vs baseline: 13.5819x; 1.6145x over previous
//
#include <hip/hip_runtime.h>

#define FSZ 5

// Problem constants (from reference setup_inputs)
#define B_ 2
#define C_ 64
#define H_ 256
#define W_ 256
#define HIN (H_ + FSZ - 1)   // 260
#define WIN (W_ + FSZ - 1)   // 260
#define PLANE (HIN * WIN)    // 67600 pixels per (b,c) plane

#define PXB 32               // pixels per gather block
#define NXG (W_ / PXB)       // 8 x-groups per row
#define CG  8                // channel groups per pixel (8 ch each)

// round-to-nearest-even f32 -> bf16 (matches __float2bfloat16 for normals)
__device__ __forceinline__ unsigned bf16r(float f) {
    unsigned u = __float_as_uint(f);
    return (u + 0x7fffu + ((u >> 16) & 1u)) >> 16;
}

// ---------------------------------------------------------------------------
// Kernel A: transpose+narrow [b][c][y][x] f32 -> ws[b][(y,x)][c] bf16.
// 64px x 64ch LDS tile; reads and packed-uint writes both coalesced.
// ---------------------------------------------------------------------------
__global__ __launch_bounds__(256) void transpose_bf16_kernel(
    const float* __restrict__ inp, unsigned* __restrict__ wsu)
{
    __shared__ float t[64][65];            // +1 pad
    const int NP64 = (PLANE + 63) / 64;    // 1057 pixel tiles
    int bid = blockIdx.x;
    const int b  = bid / NP64;
    const int p0 = (bid % NP64) * 64;
    const float* ib = inp + (size_t)b * C_ * PLANE;
    unsigned*    wb = wsu + (size_t)b * PLANE * (C_ / 2);
    const int tid = threadIdx.x;

    #pragma unroll
    for (int it = 0; it < 16; ++it) {
        const int e = it * 256 + tid;
        const int c = e >> 6;              // 0..63
        const int p = e & 63;              // 0..63
        const int pp = p0 + p;
        t[p][c] = (pp < PLANE) ? ib[(size_t)c * PLANE + pp] : 0.f;
    }
    __syncthreads();
    // write 2 channels per lane as packed uint (low ushort = even channel)
    #pragma unroll
    for (int it = 0; it < 8; ++it) {
        const int e = it * 256 + tid;      // 0..2047
        const int c2 = e & 31;             // uint-channel 0..31
        const int p  = e >> 5;             // 0..63
        const int pp = p0 + p;
        if (pp < PLANE) {
            const unsigned v = bf16r(t[p][2 * c2]) | (bf16r(t[p][2 * c2 + 1]) << 16);
            wb[(size_t)pp * (C_ / 2) + c2] = v;
        }
    }
}

// ---------------------------------------------------------------------------
// Kernel B: gather from bf16 channels-last ws.
// thread = (pixel, 8-channel group); per corner = one 16B uint4 (8 bf16).
// Block = 32 px x 8 cg; y-adjacent same-x blocks 8 bids apart -> same XCD.
// ---------------------------------------------------------------------------
#define BLO(u) __uint_as_float((u) << 16)
#define BHI(u) __uint_as_float((u) & 0xffff0000u)
#define ACC8(U, Wt) \
    a0 = fmaf(Wt, BLO(U.x), a0); a1 = fmaf(Wt, BHI(U.x), a1); \
    a2 = fmaf(Wt, BLO(U.y), a2); a3 = fmaf(Wt, BHI(U.y), a3); \
    a4 = fmaf(Wt, BLO(U.z), a4); a5 = fmaf(Wt, BHI(U.z), a5); \
    a6 = fmaf(Wt, BLO(U.w), a6); a7 = fmaf(Wt, BHI(U.w), a7);

__global__ __launch_bounds__(256) void dsepconv_bf16_kernel(
    const uint4* __restrict__ wsq,
    const float* __restrict__ vertical,
    const float* __restrict__ horizontal,
    const float* __restrict__ offx,
    const float* __restrict__ offy,
    const float* __restrict__ mask,
    float* __restrict__ out)
{
    const int t  = threadIdx.x;
    const int cg = t & (CG - 1);           // 0..7 -> channels cg*8..cg*8+7
    const int pl = t >> 3;                 // 0..31
    int bid = blockIdx.x;
    const int xg = bid % NXG; bid /= NXG;
    const int y  = bid % H_;  bid /= H_;
    const int b  = bid;
    const int x  = xg * PXB + pl;

    const int HW = H_ * W_;
    const int pix = y * W_ + x;

    const float* vert = vertical   + (size_t)(b * FSZ) * HW + pix;
    const float* horz = horizontal + (size_t)(b * FSZ) * HW + pix;
    const float* ox   = offx + (size_t)(b * FSZ * FSZ) * HW + pix;
    const float* oy   = offy + (size_t)(b * FSZ * FSZ) * HW + pix;
    const float* mk   = mask + (size_t)(b * FSZ * FSZ) * HW + pix;
    // per-pixel = 8 uint4s; this thread's channel group adds +cg
    const uint4* wsb  = wsq + (size_t)b * PLANE * CG + cg;

    float a0 = 0.f, a1 = 0.f, a2 = 0.f, a3 = 0.f,
          a4 = 0.f, a5 = 0.f, a6 = 0.f, a7 = 0.f;

    float hj_r[FSZ];
    #pragma unroll
    for (int j = 0; j < FSZ; ++j) hj_r[j] = horz[j * HW];

    for (int i = 0; i < FSZ; ++i) {
        const float vi = vert[i * HW];
        #pragma unroll
        for (int j = 0; j < FSZ; ++j) {
            const int k = i * FSZ + j;
            const float offy_v = oy[k * HW];
            const float offx_v = ox[k * HW];
            const float m_v    = mk[k * HW];

            const float pyf = (float)(y + i) + offy_v;
            const float pxf = (float)(x + j) + offx_v;
            const float y0f = floorf(pyf);
            const float x0f = floorf(pxf);
            const float ay = pyf - y0f;
            const float ax = pxf - x0f;

            int y0 = (int)y0f;
            int x0 = (int)x0f;
            int y1 = y0 + 1;
            int x1 = x0 + 1;
            y0 = min(max(y0, 0), HIN - 1);
            y1 = min(max(y1, 0), HIN - 1);
            x0 = min(max(x0, 0), WIN - 1);
            x1 = min(max(x1, 0), WIN - 1);

            const float w   = vi * hj_r[j] * m_v;
            const float w00 = w * (1.f - ay) * (1.f - ax);
            const float w01 = w * (1.f - ay) * ax;
            const float w10 = w * ay * (1.f - ax);
            const float w11 = w * ay * ax;

            const uint4 u00 = wsb[(size_t)(y0 * WIN + x0) * CG];
            const uint4 u01 = wsb[(size_t)(y0 * WIN + x1) * CG];
            const uint4 u10 = wsb[(size_t)(y1 * WIN + x0) * CG];
            const uint4 u11 = wsb[(size_t)(y1 * WIN + x1) * CG];

            ACC8(u00, w00);
            ACC8(u01, w01);
            ACC8(u10, w10);
            ACC8(u11, w11);
        }
    }

    // output is channels-first [b][c][y][x]
    float* outp = out + (size_t)(b * C_ + cg * 8) * HW + pix;
    outp[0 * HW] = a0;
    outp[1 * HW] = a1;
    outp[2 * HW] = a2;
    outp[3 * HW] = a3;
    outp[4 * HW] = a4;
    outp[5 * HW] = a5;
    outp[6 * HW] = a6;
    outp[7 * HW] = a7;
}

// ---------------------------------------------------------------------------
// Fallback (R1, proven-correct, ~613us): channels-first scattered gather.
// ---------------------------------------------------------------------------
#define CHUNK 16
__global__ __launch_bounds__(256) void dsepconv_kernel(
    const float* __restrict__ inp,
    const float* __restrict__ vertical,
    const float* __restrict__ horizontal,
    const float* __restrict__ offx,
    const float* __restrict__ offy,
    const float* __restrict__ mask,
    float* __restrict__ out)
{
    const int NCH = C_ / CHUNK;
    const int x = threadIdx.x;
    int bid = blockIdx.x;
    const int cc = bid % NCH; bid /= NCH;
    const int y  = bid % H_;  bid /= H_;
    const int b  = bid;
    const int c0 = cc * CHUNK;

    const int HW = H_ * W_;
    const int pix = y * W_ + x;

    const float* vert = vertical   + (size_t)(b * FSZ) * HW + pix;
    const float* horz = horizontal + (size_t)(b * FSZ) * HW + pix;
    const float* ox   = offx + (size_t)(b * FSZ * FSZ) * HW + pix;
    const float* oy   = offy + (size_t)(b * FSZ * FSZ) * HW + pix;
    const float* mk   = mask + (size_t)(b * FSZ * FSZ) * HW + pix;
    const float* inb  = inp + (size_t)(b * C_ + c0) * PLANE;

    float acc[CHUNK];
    #pragma unroll
    for (int c = 0; c < CHUNK; ++c) acc[c] = 0.f;

    float hj_r[FSZ];
    #pragma unroll
    for (int j = 0; j < FSZ; ++j) hj_r[j] = horz[j * HW];

    for (int i = 0; i < FSZ; ++i) {
        const float vi = vert[i * HW];
        #pragma unroll
        for (int j = 0; j < FSZ; ++j) {
            const int k = i * FSZ + j;
            const float offy_v = oy[k * HW];
            const float offx_v = ox[k * HW];
            const float m_v    = mk[k * HW];

            const float pyf = (float)(y + i) + offy_v;
            const float pxf = (float)(x + j) + offx_v;
            const float y0f = floorf(pyf);
            const float x0f = floorf(pxf);
            const float ay = pyf - y0f;
            const float ax = pxf - x0f;

            int y0 = (int)y0f;
            int x0 = (int)x0f;
            int y1 = y0 + 1;
            int x1 = x0 + 1;
            y0 = min(max(y0, 0), HIN - 1);
            y1 = min(max(y1, 0), HIN - 1);
            x0 = min(max(x0, 0), WIN - 1);
            x1 = min(max(x1, 0), WIN - 1);

            const float w   = vi * hj_r[j] * m_v;
            const float w00 = w * (1.f - ay) * (1.f - ax);
            const float w01 = w * (1.f - ay) * ax;
            const float w10 = w * ay * (1.f - ax);
            const float w11 = w * ay * ax;

            const int i00 = y0 * WIN + x0;
            const int i01 = y0 * WIN + x1;
            const int i10 = y1 * WIN + x0;
            const int i11 = y1 * WIN + x1;

            #pragma unroll
            for (int c = 0; c < CHUNK; ++c) {
                const float* p = inb + (size_t)c * PLANE;
                float a = acc[c];
                a = fmaf(w00, p[i00], a);
                a = fmaf(w01, p[i01], a);
                a = fmaf(w10, p[i10], a);
                a = fmaf(w11, p[i11], a);
                acc[c] = a;
            }
        }
    }

    float* outp = out + (size_t)(b * C_ + c0) * HW + pix;
    #pragma unroll
    for (int c = 0; c < CHUNK; ++c)
        outp[(size_t)c * HW] = acc[c];
}

extern "C" void kernel_launch(void* const* d_in, const int* in_sizes, int n_in,
                              void* d_out, int out_size, void* d_ws, size_t ws_size,
                              hipStream_t stream) {
    const float* inp        = (const float*)d_in[0];
    const float* vertical   = (const float*)d_in[1];
    const float* horizontal = (const float*)d_in[2];
    const float* offset_x   = (const float*)d_in[3];
    const float* offset_y   = (const float*)d_in[4];
    const float* mask       = (const float*)d_in[5];
    float* out              = (float*)d_out;

    const size_t need = (size_t)B_ * PLANE * C_ * sizeof(unsigned short); // 17.3 MB

    if (ws_size >= need) {
        const int NP64 = (PLANE + 63) / 64;
        transpose_bf16_kernel<<<dim3(B_ * NP64), dim3(256), 0, stream>>>(
            inp, (unsigned*)d_ws);
        dsepconv_bf16_kernel<<<dim3(B_ * H_ * NXG), dim3(256), 0, stream>>>(
            (const uint4*)d_ws, vertical, horizontal, offset_x, offset_y, mask, out);
    } else {
        const int NCH = C_ / CHUNK;
        dsepconv_kernel<<<dim3(B_ * H_ * NCH), dim3(W_), 0, stream>>>(
            inp, vertical, horizontal, offset_x, offset_y, mask, out);
    }
}